// Round 9
// baseline (278.217 us; speedup 1.0000x reference)
//
#include <hip/hip_runtime.h>

typedef float f4 __attribute__((ext_vector_type(4)));
typedef float f16v __attribute__((ext_vector_type(16)));
typedef _Float16 hf;
typedef __fp16 fp16x2 __attribute__((ext_vector_type(2)));
typedef hf h8 __attribute__((ext_vector_type(8)));
typedef unsigned short ushort_t;
typedef unsigned int uint_t;
typedef uint_t u4 __attribute__((ext_vector_type(4)));

#define BATCH 8
#define CH 128
#define NPIX 4096
#define LOG2E 1.4426950408889634f
#define RESCALE_THR 8.0f  // defer-max threshold (base-2 units); P bounded by 2^8

__device__ inline f16v mfma32h(h8 a, h8 b, f16v c) {
    return __builtin_amdgcn_mfma_f32_32x32x16_f16(a, b, c, 0, 0, 0);
}

__device__ inline uint_t pk2h(float a, float b) {  // pack 2 fp32 -> fp16x2 (RTZ), as u32
    fp16x2 pp = __builtin_amdgcn_cvt_pkrtz(a, b);
    union { fp16x2 v; uint_t u; } cv;
    cv.v = pp;
    return cv.u;
}

// after: a = {a_lo31, b_lo31}, b = {a_hi31, b_hi31}
__device__ inline void pl32swap(uint_t& a, uint_t& b) {
    asm("v_permlane32_swap_b32 %0, %1" : "+v"(a), "+v"(b));
}

typedef __attribute__((address_space(3))) uint_t lds_uint;
typedef __attribute__((address_space(1))) const uint_t global_uint;
__device__ inline void dma16(const void* g, void* l) {
    __builtin_amdgcn_global_load_lds((global_uint*)g, (lds_uint*)l, 16, 0, 0);
}

__device__ inline ushort_t h2u(hf x) {
    union { hf h; ushort_t u; } cv;
    cv.h = x;
    return cv.u;
}

// wait(own oldest DMAs) -> barrier -> pin schedule
#define WAITB(vm)                                                          \
    do {                                                                   \
        asm volatile("s_waitcnt vmcnt(" #vm ") lgkmcnt(0)" ::: "memory");  \
        __builtin_amdgcn_s_barrier();                                      \
        __builtin_amdgcn_sched_barrier(0);                                 \
    } while (0)

// plain barrier: frees LDS buffer for the next stage
#define BARB()                              \
    do {                                    \
        __builtin_amdgcn_s_barrier();       \
        __builtin_amdgcn_sched_barrier(0);  \
    } while (0)

// ---------------- QKV projection via MFMA (fp16 hi/lo 2-pass) ----------------
// X converted to fp16 hi/lo ONCE into LDS; fragments via ds_read_b128.
// Q: [b][n][c] (log2e-scaled);  K: [b][n][c];  V: [b][c][n].  All fp16.
__global__ __launch_bounds__(256) void qkv_kernel(const float* __restrict__ x1,
                                                  const float* __restrict__ x2,
                                                  const float* __restrict__ Wq,
                                                  const float* __restrict__ Wk,
                                                  const float* __restrict__ Wv,
                                                  const float* __restrict__ bq,
                                                  const float* __restrict__ bk,
                                                  const float* __restrict__ bv,
                                                  hf* __restrict__ Qf, hf* __restrict__ Kf,
                                                  hf* __restrict__ Vf) {
    // XH/XL[n][c] fp16, 64 x 128, rows 256B = 16 slots of 16B; slot s stored at
    // s' = s ^ (n&15)  -> conflict-free b128 reads.
    __shared__ __align__(16) ushort_t XH[64 * 128];
    __shared__ __align__(16) ushort_t XL[64 * 128];

    int bid = blockIdx.x;
    int m = bid >> 9;          // 0:Q 1:K 2:V
    int rem = bid & 511;
    int b = rem & 7;
    int n0 = (rem >> 3) << 6;  // 64-px chunk

    const float* X = ((m == 0) ? x1 : x2) + (size_t)b * CH * NPIX;
    const float* bias = (m == 0) ? bq : (m == 1) ? bk : bv;

    int tid = threadIdx.x;
    // stage X fp32 -> cvt hi/lo fp16 -> LDS [n][c] swizzled (coalesced global reads)
#pragma unroll
    for (int r = 0; r < 8; ++r) {
        int c = 16 * r + (tid >> 4);
        int n4 = (tid & 15) << 2;
        f4 v = *(const f4*)&X[(size_t)c * NPIX + n0 + n4];
        int cs = c >> 3, cj = c & 7;
#pragma unroll
        for (int j = 0; j < 4; ++j) {
            int n = n4 + j;
            hf hi = (hf)v[j];
            hf lo = (hf)(v[j] - (float)hi);
            int ofs = n * 128 + ((cs ^ (n & 15)) << 3) + cj;
            XH[ofs] = h2u(hi);
            XL[ofs] = h2u(lo);
        }
    }

    int lane = tid & 63;
    int w = tid >> 6;
    int h = lane >> 5;
    int m32 = lane & 31;
    int o0 = w * 32;  // this wave's 32 output channels

    // W fragments: read fp32 row o0+m32 of W directly, convert in-reg (same element
    // set serves as A-frag (V path) and B-frag (Q/K path)).
    const float* Wsrc = (m == 0) ? Wq : (m == 1) ? Wk : Wv;
    float wscale = (m == 0) ? LOG2E : 1.0f;
    h8 wf[8];
    {
        const float* wrow = Wsrc + (size_t)(o0 + m32) * CH;
#pragma unroll
        for (int kc = 0; kc < 8; ++kc) {
            f4 a = *(const f4*)&wrow[kc * 16 + h * 8];
            f4 b2 = *(const f4*)&wrow[kc * 16 + h * 8 + 4];
            h8 t;
#pragma unroll
            for (int j = 0; j < 4; ++j) {
                t[j] = (hf)(a[j] * wscale);
                t[4 + j] = (hf)(b2[j] * wscale);
            }
            wf[kc] = t;
        }
    }

    __syncthreads();

    f16v acc[2];
#pragma unroll
    for (int g = 0; g < 2; ++g)
#pragma unroll
        for (int r = 0; r < 16; ++r) acc[g][r] = 0.f;

    int swzn = m32 & 15;  // n&15 for n = g*32+m32
#pragma unroll
    for (int g = 0; g < 2; ++g) {
        int nrow = (g * 32 + m32) * 128;
#pragma unroll
        for (int kc = 0; kc < 8; ++kc) {
            int sofs = nrow + (((kc * 2 + h) ^ swzn) << 3);
            h8 xh = *(const h8*)&XH[sofs];
            h8 xl = *(const h8*)&XL[sofs];
            if (m == 2) {  // V: D[o][n] = W . X
                acc[g] = mfma32h(wf[kc], xh, acc[g]);
                acc[g] = mfma32h(wf[kc], xl, acc[g]);
            } else {  // Q/K: D[n][o] = X^T . W^T
                acc[g] = mfma32h(xh, wf[kc], acc[g]);
                acc[g] = mfma32h(xl, wf[kc], acc[g]);
            }
        }
    }

    if (m < 2) {  // D[n][o]: col=o (lane), rows=n; store [b][n][c], lanes coalesced in o
        float bval = bias[o0 + m32] * ((m == 0) ? LOG2E : 1.0f);
        hf* Y = ((m == 0) ? Qf : Kf) + (size_t)b * NPIX * CH;
#pragma unroll
        for (int g = 0; g < 2; ++g)
#pragma unroll
            for (int r = 0; r < 16; ++r) {
                int n = n0 + g * 32 + (r & 3) + 8 * (r >> 2) + 4 * h;
                Y[(size_t)n * CH + o0 + m32] = (hf)(acc[g][r] + bval);
            }
    } else {  // D[o][n]: col=n (lane), rows=o; store [b][c][n], lanes coalesced in n
        hf* Yv = Vf + (size_t)b * CH * NPIX;
#pragma unroll
        for (int g = 0; g < 2; ++g)
#pragma unroll
            for (int r = 0; r < 16; ++r) {
                int o = o0 + (r & 3) + 8 * (r >> 2) + 4 * h;
                Yv[(size_t)o * NPIX + n0 + g * 32 + m32] = (hf)(acc[g][r] + bias[o]);
            }
    }
}

// ---------------- fp16 MFMA flash attention, low-register / high-occupancy form ----------
// grid: 8b * 4ks(1024 keys) * 64 qtiles(64q) = 2048 blocks. 4 waves = (qg x cg):
//   qg = w>>1 : which 32 queries;  cg = w&1 : which 64-channel half of O.
// Each wave: full QK^T for its 32q (duplicated across cg pair), full softmax,
// PV for 64 channels -> accO = 2 f16v = 32 AGPR (register-bin fix: total regs
// must drop below the 128 occupancy-quantization boundary).
// Q lives in LDS (frees 32 VGPR), read per tile like K (same swizzle family).
// LDS 48 KB: Q 16 KB @0, K dbuf 2x8 KB @8192, V dbuf 2x8 KB @16384 (ushort idx)
//   -> 3 blocks/CU = 12 waves/CU (was 8).
// Pipeline (per iter): stage(t+1) -> WAITB(4) [own tile-t landed, t+1 in flight]
//   -> comp(t) -> BARB() [frees buffer for t+2]. vmcnt never drains mid-loop.
__global__ __launch_bounds__(256, 4) void attn_kernel(const hf* __restrict__ Qf,
                                                      const hf* __restrict__ Kf,
                                                      const hf* __restrict__ Vf,
                                                      hf* __restrict__ Opart,
                                                      float* __restrict__ Mpart,
                                                      float* __restrict__ Lpart) {
    __shared__ __align__(16) ushort_t smem[24576];  // 48 KB

    int tid = threadIdx.x;
    int lane = tid & 63;
    int w = tid >> 6;
    int h = lane >> 5;
    int m32 = lane & 31;
    int qg = w >> 1;  // query group (32 q)
    int cg = w & 1;   // channel half (64 ch)

    int idx = blockIdx.x;
    int b = idx & 7;             // batch <-> XCD
    int ks = (idx >> 3) & 3;     // key quarter (1024 keys)
    int qt = idx >> 5;           // query tile (64 q), 0..63
    int k0g = ks << 10;

    const hf* Qb = Qf + (size_t)b * NPIX * CH;
    const hf* Kb = Kf + (size_t)b * NPIX * CH;
    const hf* Vb = Vf + (size_t)b * CH * NPIX;

    // ---- prologue DMA: Q tile (16 chunks of 1KB) + K/V tile 0 ----
    {
        const hf* pQ[4];
#pragma unroll
        for (int a = 0; a < 4; ++a) {
            int cq = w * 4 + a;  // 0..15
            int rowq = cq * 4 + (lane >> 4);             // 0..63
            int lcq = (lane & 15) ^ (rowq & 15);
            pQ[a] = Qb + (size_t)((qt << 6) + rowq) * CH + lcq * 8;
        }
#pragma unroll
        for (int a = 0; a < 4; ++a) dma16(pQ[a], &smem[(w * 4 + a) * 512]);
    }

    // K/V DMA source pointers (XOR swizzle folded into global address)
    // K tile: [32 rows][128 ch] 8 KB, 256B rows = 16 slots; slot ^ (row&15).
    // V tile: [128 ch][32 k]  8 KB,  64B rows; slot ^ (c&3) ^ ((c>>2)&1).
    const hf* pK[2];
    const hf* pV[2];
#pragma unroll
    for (int a = 0; a < 2; ++a) {
        int c8 = w * 2 + a;  // 0..7
        int rowk = c8 * 4 + (lane >> 4);                 // 0..31
        int lck = (lane & 15) ^ (rowk & 15);
        pK[a] = Kb + (size_t)(k0g + rowk) * CH + lck * 8;
        int rowv = c8 * 16 + (lane >> 2);                // 0..127 (= channel)
        int lcv = (lane & 3) ^ (rowv & 3) ^ ((rowv >> 2) & 1);
        pV[a] = Vb + (size_t)rowv * NPIX + k0g + lcv * 8;
    }

    // stage one 32-key K/V tile into buffer buf (0/1), advance pointers
    auto stage = [&](int buf) {
#pragma unroll
        for (int a = 0; a < 2; ++a) {
            int c8 = w * 2 + a;
            dma16(pK[a], &smem[8192 + buf * 4096 + c8 * 512]);
            dma16(pV[a], &smem[16384 + buf * 4096 + c8 * 512]);
            pK[a] += 32 * CH;
            pV[a] += 32;
        }
    };

    stage(0);  // outstanding: Q(4) + tile0(4)

    f16v accO[2];
#pragma unroll
    for (int j = 0; j < 2; ++j)
#pragma unroll
        for (int r = 0; r < 16; ++r) accO[j][r] = 0.f;
    float mprev = -1e30f;  // per-query running max (base-2 units)
    float lsum = 0.f;      // per-lane-half partial sum (merged in epilogue)

    int rq128 = (qg * 32 + m32) * 128;  // this lane's Q row base (ushort idx)
    int sw15 = m32 & 15;

    // compute one 32-key tile from buffer buf
    auto comp = [&](int buf) {
        const ushort_t* kb = smem + 8192 + buf * 4096;
        const ushort_t* vb = smem + 16384 + buf * 4096;

        // --- S^T[key][query] = K . Q^T (32 keys x this wave's 32 queries) ---
        f16v acc;
#pragma unroll
        for (int r = 0; r < 16; ++r) acc[r] = 0.f;
        __builtin_amdgcn_s_setprio(1);
#pragma unroll
        for (int kc = 0; kc < 8; ++kc) {
            int pA = (kc * 2 + h) ^ sw15;
            h8 ahi = *(const h8*)&kb[m32 * 128 + pA * 8];
            h8 qv = *(const h8*)&smem[rq128 + pA * 8];  // Q from LDS (same slot idx)
            acc = mfma32h(ahi, qv, acc);
        }
        __builtin_amdgcn_s_setprio(0);

        // --- wave-private online softmax (base-2 units, deferred max) ---
        float ta = fmaxf(fmaxf(acc[0], acc[1]), acc[2]);
        float tb = fmaxf(fmaxf(acc[3], acc[4]), acc[5]);
        ta = fmaxf(fmaxf(ta, acc[6]), acc[7]);
        tb = fmaxf(fmaxf(tb, acc[8]), acc[9]);
        ta = fmaxf(fmaxf(ta, acc[10]), acc[11]);
        tb = fmaxf(fmaxf(tb, acc[12]), acc[13]);
        ta = fmaxf(fmaxf(ta, acc[14]), acc[15]);
        float tmax = fmaxf(ta, tb);  // this lane-half's tile max
        if (__any(tmax > mprev + RESCALE_THR)) {
            float tx = fmaxf(tmax, __shfl_xor(tmax, 32));  // exact cross-half max
            float mnew = fmaxf(mprev, tx);
            float alpha = exp2f(mprev - mnew);
            lsum *= alpha;
#pragma unroll
            for (int j = 0; j < 2; ++j)
#pragma unroll
                for (int r = 0; r < 16; ++r) accO[j][r] *= alpha;
            mprev = mnew;
        }

        // exp2 + pack + per-lane-half row-sum (cross-half merge deferred)
        uint_t pk[8];
        float ps0 = 0.f, ps1 = 0.f;
#pragma unroll
        for (int t2 = 0; t2 < 8; ++t2) {
            float e0 = exp2f(acc[2 * t2] - mprev);
            float e1 = exp2f(acc[2 * t2 + 1] - mprev);
            ps0 += e0;
            ps1 += e1;
            pk[t2] = pk2h(e0, e1);
        }
        lsum += ps0 + ps1;

        // both-half P fragments via permlane32_swap
        pl32swap(pk[0], pk[2]);
        pl32swap(pk[1], pk[3]);
        pl32swap(pk[4], pk[6]);
        pl32swap(pk[5], pk[7]);
        h8 pbp[2];
#pragma unroll
        for (int g2 = 0; g2 < 2; ++g2) {
            u4 fv;
            fv[0] = pk[g2 * 4 + 0];
            fv[1] = pk[g2 * 4 + 1];
            fv[2] = pk[g2 * 4 + 2];
            fv[3] = pk[g2 * 4 + 3];
            __builtin_memcpy(&pbp[g2], &fv, 16);
        }

        // --- O^T[c][q] += V . P for this wave's 64-channel half ---
        __builtin_amdgcn_s_setprio(1);
#pragma unroll
        for (int g2 = 0; g2 < 2; ++g2) {
            int pv = (g2 * 2 + h) ^ (m32 & 3) ^ ((m32 >> 2) & 1);
#pragma unroll
            for (int j = 0; j < 2; ++j) {
                int ct = cg * 2 + j;
                h8 av = *(const h8*)&vb[(ct * 32 + m32) * 32 + pv * 8];
                accO[j] = mfma32h(av, pbp[g2], accO[j]);
            }
        }
        __builtin_amdgcn_s_setprio(0);
    };

    // main loop: 32 tiles, 2x unrolled (compile-time buffer indices).
    // iter t: stage(t+1); WAITB(4) [drains Q+tile0 at t=0, tile t thereafter]; comp(t); BARB.
    for (int tb = 0; tb < 15; ++tb) {
        stage(1); WAITB(4); comp(0); BARB();
        stage(0); WAITB(4); comp(1); BARB();
    }
    stage(1); WAITB(4); comp(0); BARB();  // t=30, stages tile 31
    WAITB(0); comp(1);                    // t=31 (final drain)

    // --- epilogue: merge lane-halves; each wave owns its 64ch x 32q fully ---
    lsum += __shfl_xor(lsum, 32);

    size_t base = (((size_t)ks * 8 + b) * 64 + qt) * 8192;  // 128ch x 64q
    size_t mlb = (((size_t)ks * 8 + b) * 64 + qt) * 64;
    int q = qg * 32 + m32;
#pragma unroll
    for (int j = 0; j < 2; ++j)
#pragma unroll
        for (int r = 0; r < 16; ++r) {
            int ch = (cg * 2 + j) * 32 + (r & 3) + 8 * (r >> 2) + 4 * h;
            Opart[base + ch * 64 + q] = (hf)accO[j][r];
        }
    if (cg == 0 && h == 0) {
        Mpart[mlb + q] = mprev;
        Lpart[mlb + q] = lsum;
    }
}

// ---------------- combine the four key-quarter partials (64q tiles, vectorized) ----------
__global__ __launch_bounds__(256) void combine_kernel(const hf* __restrict__ Opart,
                                                      const float* __restrict__ Mp,
                                                      const float* __restrict__ Lp,
                                                      float* __restrict__ out) {
    int idx = blockIdx.x;        // 1024 = 2chh x 8b x 64qt
    int chh = idx & 1;
    int b = (idx >> 1) & 7;
    int qt = idx >> 4;           // 0..63
    int tid = threadIdx.x;
    int q8 = (tid & 7) << 3;     // 8 consecutive queries (0..56)
    int chl = tid >> 3;          // 0..31

    float Marr[4][8], Larr[4][8];
#pragma unroll
    for (int p = 0; p < 4; ++p) {
        size_t mb = (((size_t)p * 8 + b) * 64 + qt) * 64 + q8;
        f4 ma = *(const f4*)&Mp[mb];
        f4 mb2 = *(const f4*)&Mp[mb + 4];
        f4 la = *(const f4*)&Lp[mb];
        f4 lb = *(const f4*)&Lp[mb + 4];
#pragma unroll
        for (int j = 0; j < 4; ++j) {
            Marr[p][j] = ma[j];
            Marr[p][4 + j] = mb2[j];
            Larr[p][j] = la[j];
            Larr[p][4 + j] = lb[j];
        }
    }

    float wgt[4][8];
#pragma unroll
    for (int j = 0; j < 8; ++j) {
        float M = fmaxf(fmaxf(Marr[0][j], Marr[1][j]), fmaxf(Marr[2][j], Marr[3][j]));
        float L = 0.f;
#pragma unroll
        for (int p = 0; p < 4; ++p) {
            float w_ = exp2f(Marr[p][j] - M);
            wgt[p][j] = w_;
            L += w_ * Larr[p][j];
        }
        float rd = 1.0f / L;
#pragma unroll
        for (int p = 0; p < 4; ++p) wgt[p][j] *= rd;
    }

    const hf* ob[4];
#pragma unroll
    for (int p = 0; p < 4; ++p)
        ob[p] = Opart + (((size_t)p * 8 + b) * 64 + qt) * 8192 + q8;
    float* O = out + (size_t)b * CH * NPIX + (qt << 6) + q8;

#pragma unroll
    for (int it = 0; it < 2; ++it) {
        int ch = chh * 64 + it * 32 + chl;
        union { u4 u; h8 v; } o4[4];
#pragma unroll
        for (int p = 0; p < 4; ++p) o4[p].u = *(const u4*)&ob[p][(size_t)ch * 64];
        f4 r0, r1;
#pragma unroll
        for (int j = 0; j < 8; ++j) {
            float s = 0.f;
#pragma unroll
            for (int p = 0; p < 4; ++p) s += wgt[p][j] * (float)o4[p].v[j];
            if (j < 4) r0[j] = s;
            else r1[j - 4] = s;
        }
        float* dst = O + (size_t)ch * NPIX;
        *(f4*)dst = r0;
        *(f4*)(dst + 4) = r1;
    }
}

extern "C" void kernel_launch(void* const* d_in, const int* in_sizes, int n_in,
                              void* d_out, int out_size, void* d_ws, size_t ws_size,
                              hipStream_t stream) {
    const float* x1 = (const float*)d_in[0];
    const float* x2 = (const float*)d_in[1];
    const float* Wq = (const float*)d_in[2];
    const float* bq = (const float*)d_in[3];
    const float* Wk = (const float*)d_in[4];
    const float* bk = (const float*)d_in[5];
    const float* Wv = (const float*)d_in[6];
    const float* bv = (const float*)d_in[7];
    float* outp = (float*)d_out;

    const size_t N = (size_t)BATCH * NPIX * CH;  // 4.19M
    hf* Qf = (hf*)d_ws;
    hf* Kf = Qf + N;
    hf* Vf = Qf + 2 * N;
    hf* Opart = Qf + 3 * N;                              // 4*8*64*8192 hf = 33.6 MB
    float* Mp = (float*)(Opart + (size_t)4 * 8 * 64 * 8192);
    float* Lp = Mp + (size_t)4 * 8 * 64 * 64;

    qkv_kernel<<<3 * BATCH * (NPIX / 64), 256, 0, stream>>>(x1, x2, Wq, Wk, Wv,
                                                            bq, bk, bv, Qf, Kf, Vf);
    attn_kernel<<<BATCH * 4 * (NPIX / 64), 256, 0, stream>>>(Qf, Kf, Vf, Opart, Mp, Lp);
    combine_kernel<<<2 * BATCH * (NPIX / 64), 256, 0, stream>>>(Opart, Mp, Lp, outp);
}

// Round 10
// 205.126 us; speedup vs baseline: 1.3563x; 1.3563x over previous
//
#include <hip/hip_runtime.h>

typedef float f4 __attribute__((ext_vector_type(4)));
typedef float f16v __attribute__((ext_vector_type(16)));
typedef _Float16 hf;
typedef __fp16 fp16x2 __attribute__((ext_vector_type(2)));
typedef hf h8 __attribute__((ext_vector_type(8)));
typedef unsigned short ushort_t;
typedef unsigned int uint_t;
typedef uint_t u4 __attribute__((ext_vector_type(4)));

#define BATCH 8
#define CH 128
#define NPIX 4096
#define LOG2E 1.4426950408889634f
#define RESCALE_THR 8.0f  // defer-max threshold (base-2 units); P bounded by 2^8

__device__ inline f16v mfma32h(h8 a, h8 b, f16v c) {
    return __builtin_amdgcn_mfma_f32_32x32x16_f16(a, b, c, 0, 0, 0);
}

__device__ inline uint_t pk2h(float a, float b) {  // pack 2 fp32 -> fp16x2 (RTZ), as u32
    fp16x2 pp = __builtin_amdgcn_cvt_pkrtz(a, b);
    union { fp16x2 v; uint_t u; } cv;
    cv.v = pp;
    return cv.u;
}

// after: a = {a_lo31, b_lo31}, b = {a_hi31, b_hi31}
__device__ inline void pl32swap(uint_t& a, uint_t& b) {
    asm("v_permlane32_swap_b32 %0, %1" : "+v"(a), "+v"(b));
}

typedef __attribute__((address_space(3))) uint_t lds_uint;
typedef __attribute__((address_space(1))) const uint_t global_uint;
__device__ inline void dma16(const void* g, void* l) {
    __builtin_amdgcn_global_load_lds((global_uint*)g, (lds_uint*)l, 16, 0, 0);
}

__device__ inline ushort_t h2u(hf x) {
    union { hf h; ushort_t u; } cv;
    cv.h = x;
    return cv.u;
}

// wait(own oldest DMAs) -> barrier -> pin schedule
#define WAITB(vm)                                                          \
    do {                                                                   \
        asm volatile("s_waitcnt vmcnt(" #vm ") lgkmcnt(0)" ::: "memory");  \
        __builtin_amdgcn_s_barrier();                                      \
        __builtin_amdgcn_sched_barrier(0);                                 \
    } while (0)

// ---------------- QKV projection via MFMA (fp16 hi/lo 2-pass) ----------------
// X converted to fp16 hi/lo ONCE into LDS; fragments via ds_read_b128.
// Q: [b][n][c] (log2e-scaled);  K: [b][n][c];  V: [b][c][n].  All fp16.
__global__ __launch_bounds__(256) void qkv_kernel(const float* __restrict__ x1,
                                                  const float* __restrict__ x2,
                                                  const float* __restrict__ Wq,
                                                  const float* __restrict__ Wk,
                                                  const float* __restrict__ Wv,
                                                  const float* __restrict__ bq,
                                                  const float* __restrict__ bk,
                                                  const float* __restrict__ bv,
                                                  hf* __restrict__ Qf, hf* __restrict__ Kf,
                                                  hf* __restrict__ Vf) {
    // XH/XL[n][c] fp16, 64 x 128, rows 256B = 16 slots of 16B; slot s stored at
    // s' = s ^ (n&15)  -> conflict-free b128 reads.
    __shared__ __align__(16) ushort_t XH[64 * 128];
    __shared__ __align__(16) ushort_t XL[64 * 128];

    int bid = blockIdx.x;
    int m = bid >> 9;          // 0:Q 1:K 2:V
    int rem = bid & 511;
    int b = rem & 7;
    int n0 = (rem >> 3) << 6;  // 64-px chunk

    const float* X = ((m == 0) ? x1 : x2) + (size_t)b * CH * NPIX;
    const float* bias = (m == 0) ? bq : (m == 1) ? bk : bv;

    int tid = threadIdx.x;
    // stage X fp32 -> cvt hi/lo fp16 -> LDS [n][c] swizzled (coalesced global reads)
#pragma unroll
    for (int r = 0; r < 8; ++r) {
        int c = 16 * r + (tid >> 4);
        int n4 = (tid & 15) << 2;
        f4 v = *(const f4*)&X[(size_t)c * NPIX + n0 + n4];
        int cs = c >> 3, cj = c & 7;
#pragma unroll
        for (int j = 0; j < 4; ++j) {
            int n = n4 + j;
            hf hi = (hf)v[j];
            hf lo = (hf)(v[j] - (float)hi);
            int ofs = n * 128 + ((cs ^ (n & 15)) << 3) + cj;
            XH[ofs] = h2u(hi);
            XL[ofs] = h2u(lo);
        }
    }

    int lane = tid & 63;
    int w = tid >> 6;
    int h = lane >> 5;
    int m32 = lane & 31;
    int o0 = w * 32;  // this wave's 32 output channels

    // W fragments: read fp32 row o0+m32 of W directly, convert in-reg (same element
    // set serves as A-frag (V path) and B-frag (Q/K path)).
    const float* Wsrc = (m == 0) ? Wq : (m == 1) ? Wk : Wv;
    float wscale = (m == 0) ? LOG2E : 1.0f;
    h8 wf[8];
    {
        const float* wrow = Wsrc + (size_t)(o0 + m32) * CH;
#pragma unroll
        for (int kc = 0; kc < 8; ++kc) {
            f4 a = *(const f4*)&wrow[kc * 16 + h * 8];
            f4 b2 = *(const f4*)&wrow[kc * 16 + h * 8 + 4];
            h8 t;
#pragma unroll
            for (int j = 0; j < 4; ++j) {
                t[j] = (hf)(a[j] * wscale);
                t[4 + j] = (hf)(b2[j] * wscale);
            }
            wf[kc] = t;
        }
    }

    __syncthreads();

    f16v acc[2];
#pragma unroll
    for (int g = 0; g < 2; ++g)
#pragma unroll
        for (int r = 0; r < 16; ++r) acc[g][r] = 0.f;

    int swzn = m32 & 15;  // n&15 for n = g*32+m32
#pragma unroll
    for (int g = 0; g < 2; ++g) {
        int nrow = (g * 32 + m32) * 128;
#pragma unroll
        for (int kc = 0; kc < 8; ++kc) {
            int sofs = nrow + (((kc * 2 + h) ^ swzn) << 3);
            h8 xh = *(const h8*)&XH[sofs];
            h8 xl = *(const h8*)&XL[sofs];
            if (m == 2) {  // V: D[o][n] = W . X
                acc[g] = mfma32h(wf[kc], xh, acc[g]);
                acc[g] = mfma32h(wf[kc], xl, acc[g]);
            } else {  // Q/K: D[n][o] = X^T . W^T
                acc[g] = mfma32h(xh, wf[kc], acc[g]);
                acc[g] = mfma32h(xl, wf[kc], acc[g]);
            }
        }
    }

    if (m < 2) {  // D[n][o]: col=o (lane), rows=n; store [b][n][c], lanes coalesced in o
        float bval = bias[o0 + m32] * ((m == 0) ? LOG2E : 1.0f);
        hf* Y = ((m == 0) ? Qf : Kf) + (size_t)b * NPIX * CH;
#pragma unroll
        for (int g = 0; g < 2; ++g)
#pragma unroll
            for (int r = 0; r < 16; ++r) {
                int n = n0 + g * 32 + (r & 3) + 8 * (r >> 2) + 4 * h;
                Y[(size_t)n * CH + o0 + m32] = (hf)(acc[g][r] + bval);
            }
    } else {  // D[o][n]: col=n (lane), rows=o; store [b][c][n], lanes coalesced in n
        hf* Yv = Vf + (size_t)b * CH * NPIX;
#pragma unroll
        for (int g = 0; g < 2; ++g)
#pragma unroll
            for (int r = 0; r < 16; ++r) {
                int o = o0 + (r & 3) + 8 * (r >> 2) + 4 * h;
                Yv[(size_t)o * NPIX + n0 + g * 32 + m32] = (hf)(acc[g][r] + bias[o]);
            }
    }
}

// ---------------- fp16 MFMA flash attention, 2-way split-K, 4x(32q x 32k) waves ----------------
// grid: 8b * 2ksides * 32qtiles = 512 blocks = exactly 2/CU, all resident (no batching).
// Each wave owns 32 queries over the full 32-key tile -> no cross-wave merge epilogue.
// 4-deep tile pipeline, compile-time buffer indices (4x-unrolled loop):
//   WAITB(8)  [own tile-t DMAs retired; tiles t+1,t+2 in flight]  -> barrier
//   issue tile t+3 into buf (t+3)&3  [== (t-1)&3, freed by the barrier]
//   compute tile t from buf t&3
// vmcnt never drains to 0 until the last tile. 64 iters (2048 keys).
// QK^T uses even/odd dual accumulators (halves the 8-MFMA serial chain; +16
// transient VGPR only - R4's spill came from stacking this with other state).
// LDS 64 KB: K bufs @ {0..3}*4096, V bufs @ 16384 + {0..3}*4096 (ushort idx).
__global__ __launch_bounds__(256, 2) void attn_kernel(const hf* __restrict__ Qf,
                                                      const hf* __restrict__ Kf,
                                                      const hf* __restrict__ Vf,
                                                      hf* __restrict__ Opart,
                                                      float* __restrict__ Mpart,
                                                      float* __restrict__ Lpart) {
    __shared__ __align__(16) ushort_t smem[32768];  // 64 KB

    int tid = threadIdx.x;
    int lane = tid & 63;
    int w = tid >> 6;        // wave = query group
    int h = lane >> 5;
    int m32 = lane & 31;

    int idx = blockIdx.x;
    int b = idx & 7;             // batch <-> XCD
    int ks = (idx >> 3) & 1;     // key half
    int qt = idx >> 4;           // query tile (128 q)
    int q0 = (qt << 7) + w * 32; // this wave's first query
    int k0g = ks << 11;          // 2048-key base

    const hf* Qb = Qf + (size_t)b * NPIX * CH;
    const hf* Kb = Kf + (size_t)b * NPIX * CH;
    const hf* Vb = Vf + (size_t)b * CH * NPIX;

    // Q B-frags (col = q0+m32), registers for whole loop
    h8 qf[8];
#pragma unroll
    for (int kc = 0; kc < 8; ++kc)
        qf[kc] = *(const h8*)&Qb[(size_t)(q0 + m32) * CH + kc * 16 + h * 8];

    // DMA source pointers (XOR swizzle folded into global address)
    // K tile: [32 rows][128 ch] = 8 KB, 256B rows = 16 slots; slot ^ (row&15).
    // V tile: [128 ch][32 k]   = 8 KB,  64B rows; slot ^ (c&3) ^ ((c>>2)&1).
    const hf* pK[2];
    const hf* pV[2];
#pragma unroll
    for (int a = 0; a < 2; ++a) {
        int chunk_hi = w * 2 + a;  // 0..7
        int rowk = chunk_hi * 4 + (lane >> 4);           // 0..31
        int lck = (lane & 15) ^ (rowk & 15);
        pK[a] = Kb + (size_t)(k0g + rowk) * CH + lck * 8;
        int rowv = chunk_hi * 16 + (lane >> 2);          // 0..127 (= channel)
        int lcv = (lane & 3) ^ (rowv & 3) ^ ((rowv >> 2) & 1);
        pV[a] = Vb + (size_t)rowv * NPIX + k0g + lcv * 8;
    }

    f16v accO[4];
#pragma unroll
    for (int ct = 0; ct < 4; ++ct)
#pragma unroll
        for (int r = 0; r < 16; ++r) accO[ct][r] = 0.f;
    float mprev = -1e30f;  // per-query running max (base-2 units)
    float lsum = 0.f;      // per-HALF partial sum (merged once in epilogue)

    int pvs[2];
#pragma unroll
    for (int g2 = 0; g2 < 2; ++g2)
        pvs[g2] = (g2 * 2 + h) ^ (m32 & 3) ^ ((m32 >> 2) & 1);

    // stage one 32-key tile into buffer bufw (compile-time), advance pointers
    auto stage = [&](int bufw) {
#pragma unroll
        for (int a = 0; a < 2; ++a) {
            dma16(pK[a], &smem[bufw * 4096 + (w * 2 + a) * 512]);
            dma16(pV[a], &smem[16384 + bufw * 4096 + (w * 2 + a) * 512]);
            pK[a] += 32 * CH;
            pV[a] += 32;
        }
    };

    // compute one 32-key tile from buffer bufr (compile-time)
    auto comp = [&](int bufr) {
        const ushort_t* kb = smem + bufr * 4096;
        const ushort_t* vb = smem + 16384 + bufr * 4096;

        // --- S^T[key][query] = K . Q^T, even/odd dual accumulators (2 dep chains) ---
        f16v acc_e, acc_o;
#pragma unroll
        for (int r = 0; r < 16; ++r) { acc_e[r] = 0.f; acc_o[r] = 0.f; }
        __builtin_amdgcn_s_setprio(1);
#pragma unroll
        for (int kc = 0; kc < 8; ++kc) {
            int pA = (kc * 2 + h) ^ (m32 & 15);
            h8 ahi = *(const h8*)&kb[m32 * 128 + pA * 8];
            if (kc & 1) acc_o = mfma32h(ahi, qf[kc], acc_o);
            else        acc_e = mfma32h(ahi, qf[kc], acc_e);
        }
        __builtin_amdgcn_s_setprio(0);
        f16v acc;
#pragma unroll
        for (int r = 0; r < 16; ++r) acc[r] = acc_e[r] + acc_o[r];

        // --- wave-private online softmax (base-2 units, deferred max) ---
        // per-half max; __any spans all 64 lanes so the p<=2^THR bound still holds
        float ta = fmaxf(fmaxf(acc[0], acc[1]), acc[2]);
        float tb = fmaxf(fmaxf(acc[3], acc[4]), acc[5]);
        ta = fmaxf(fmaxf(ta, acc[6]), acc[7]);
        tb = fmaxf(fmaxf(tb, acc[8]), acc[9]);
        ta = fmaxf(fmaxf(ta, acc[10]), acc[11]);
        tb = fmaxf(fmaxf(tb, acc[12]), acc[13]);
        ta = fmaxf(fmaxf(ta, acc[14]), acc[15]);
        float tmax = fmaxf(ta, tb);  // this half's tile max for query m32
        if (__any(tmax > mprev + RESCALE_THR)) {
            float tx = fmaxf(tmax, __shfl_xor(tmax, 32));  // exact cross-half max
            float mnew = fmaxf(mprev, tx);
            float alpha = exp2f(mprev - mnew);
            lsum *= alpha;
#pragma unroll
            for (int ct = 0; ct < 4; ++ct)
#pragma unroll
                for (int r = 0; r < 16; ++r) accO[ct][r] *= alpha;
            mprev = mnew;
        }

        // exp2 + pack + per-half row-sum (cross-half merge deferred to epilogue)
        uint_t pk[8];
        float ps0 = 0.f, ps1 = 0.f;
#pragma unroll
        for (int t2 = 0; t2 < 8; ++t2) {
            float e0 = exp2f(acc[2 * t2] - mprev);
            float e1 = exp2f(acc[2 * t2 + 1] - mprev);
            ps0 += e0;
            ps1 += e1;
            pk[t2] = pk2h(e0, e1);
        }
        lsum += ps0 + ps1;

        // both-half P fragments via permlane32_swap
        pl32swap(pk[0], pk[2]);
        pl32swap(pk[1], pk[3]);
        pl32swap(pk[4], pk[6]);
        pl32swap(pk[5], pk[7]);
        h8 pbp[2];
#pragma unroll
        for (int g2 = 0; g2 < 2; ++g2) {
            u4 fv;
            fv[0] = pk[g2 * 4 + 0];
            fv[1] = pk[g2 * 4 + 1];
            fv[2] = pk[g2 * 4 + 2];
            fv[3] = pk[g2 * 4 + 3];
            __builtin_memcpy(&pbp[g2], &fv, 16);
        }

        // --- O^T[c][q] += V . P ---
        __builtin_amdgcn_s_setprio(1);
#pragma unroll
        for (int g2 = 0; g2 < 2; ++g2) {
            int pv = pvs[g2];
#pragma unroll
            for (int ct = 0; ct < 4; ++ct) {
                h8 av = *(const h8*)&vb[(ct * 32 + m32) * 32 + pv * 8];
                accO[ct] = mfma32h(av, pbp[g2], accO[ct]);
            }
        }
        __builtin_amdgcn_s_setprio(0);
    };

    // prologue: tiles 0,1,2 -> bufs 0,1,2 (12 DMAs in flight)
    stage(0);
    stage(1);
    stage(2);

    // main loop: t = 0..59 (4x unrolled, compile-time buffer indices)
    for (int tb = 0; tb < 15; ++tb) {
        WAITB(8); stage(3); comp(0);
        WAITB(8); stage(0); comp(1);
        WAITB(8); stage(1); comp(2);
        WAITB(8); stage(2); comp(3);
    }
    // t = 60..63
    WAITB(8); stage(3); comp(0);  // issues tile 63 (last)
    WAITB(8); comp(1);
    WAITB(4); comp(2);
    WAITB(0); comp(3);

    // --- epilogue: merge half-sums once; each wave owns its 32 q fully ---
    lsum += __shfl_xor(lsum, 32);

    size_t base = (((size_t)ks * 8 + b) * 32 + qt) * 16384;
    size_t mlb = (((size_t)ks * 8 + b) * 32 + qt) * 128;
    int q = w * 32 + m32;
#pragma unroll
    for (int ct = 0; ct < 4; ++ct)
#pragma unroll
        for (int r = 0; r < 16; ++r) {
            int ch = ct * 32 + (r & 3) + 8 * (r >> 2) + 4 * h;
            Opart[base + ch * 128 + q] = (hf)accO[ct][r];
        }
    if (h == 0) {
        Mpart[mlb + q] = mprev;
        Lpart[mlb + q] = lsum;
    }
}

// ---------------- combine the two key-half partials (vectorized) ----------------
__global__ __launch_bounds__(256) void combine_kernel(const hf* __restrict__ Opart,
                                                      const float* __restrict__ Mp,
                                                      const float* __restrict__ Lp,
                                                      float* __restrict__ out) {
    int idx = blockIdx.x;        // 512 = 2chh x 8b x 32qt
    int chh = idx & 1;
    int b = (idx >> 1) & 7;
    int qt = idx >> 4;
    int tid = threadIdx.x;
    int q8 = (tid & 15) << 3;    // 8 consecutive queries
    int chl = tid >> 4;          // 0..15

    size_t tile = (size_t)b * 32 + qt;

    float Marr[2][8], Larr[2][8];
#pragma unroll
    for (int p = 0; p < 2; ++p) {
        const float* mp_ = Mp + ((size_t)p * 256 + tile) * 128 + q8;
        const float* lp_ = Lp + ((size_t)p * 256 + tile) * 128 + q8;
        f4 ma = *(const f4*)mp_;
        f4 mb = *(const f4*)(mp_ + 4);
        f4 la = *(const f4*)lp_;
        f4 lb = *(const f4*)(lp_ + 4);
#pragma unroll
        for (int j = 0; j < 4; ++j) {
            Marr[p][j] = ma[j];
            Marr[p][4 + j] = mb[j];
            Larr[p][j] = la[j];
            Larr[p][4 + j] = lb[j];
        }
    }

    float wgt[2][8];
#pragma unroll
    for (int j = 0; j < 8; ++j) {
        float M = fmaxf(Marr[0][j], Marr[1][j]);
        float w0 = exp2f(Marr[0][j] - M);
        float w1 = exp2f(Marr[1][j] - M);
        float rd = 1.0f / (w0 * Larr[0][j] + w1 * Larr[1][j]);
        wgt[0][j] = w0 * rd;
        wgt[1][j] = w1 * rd;
    }

    const hf* ob[2];
#pragma unroll
    for (int p = 0; p < 2; ++p) ob[p] = Opart + ((size_t)p * 256 + tile) * 16384 + q8;
    float* O = out + (size_t)b * CH * NPIX + (size_t)qt * 128 + q8;

#pragma unroll
    for (int it = 0; it < 4; ++it) {
        int ch = chh * 64 + it * 16 + chl;
        union { u4 u; h8 v; } o4[2];
#pragma unroll
        for (int p = 0; p < 2; ++p) o4[p].u = *(const u4*)&ob[p][(size_t)ch * 128];
        f4 r0, r1;
#pragma unroll
        for (int j = 0; j < 8; ++j) {
            float s = wgt[0][j] * (float)o4[0].v[j] + wgt[1][j] * (float)o4[1].v[j];
            if (j < 4) r0[j] = s;
            else r1[j - 4] = s;
        }
        float* dst = O + (size_t)ch * NPIX;
        *(f4*)dst = r0;
        *(f4*)(dst + 4) = r1;
    }
}

extern "C" void kernel_launch(void* const* d_in, const int* in_sizes, int n_in,
                              void* d_out, int out_size, void* d_ws, size_t ws_size,
                              hipStream_t stream) {
    const float* x1 = (const float*)d_in[0];
    const float* x2 = (const float*)d_in[1];
    const float* Wq = (const float*)d_in[2];
    const float* bq = (const float*)d_in[3];
    const float* Wk = (const float*)d_in[4];
    const float* bk = (const float*)d_in[5];
    const float* Wv = (const float*)d_in[6];
    const float* bv = (const float*)d_in[7];
    float* outp = (float*)d_out;

    const size_t N = (size_t)BATCH * NPIX * CH;  // 4.19M
    hf* Qf = (hf*)d_ws;
    hf* Kf = Qf + N;
    hf* Vf = Qf + 2 * N;
    hf* Opart = Qf + 3 * N;                              // 2*8*32*16384 hf = 16.8 MB
    float* Mp = (float*)(Opart + (size_t)2 * 8 * 32 * 16384);
    float* Lp = Mp + (size_t)2 * 8 * 32 * 128;

    qkv_kernel<<<3 * BATCH * (NPIX / 64), 256, 0, stream>>>(x1, x2, Wq, Wk, Wv,
                                                            bq, bk, bv, Qf, Kf, Vf);
    attn_kernel<<<BATCH * 2 * (NPIX / 128), 256, 0, stream>>>(Qf, Kf, Vf, Opart, Mp, Lp);
    combine_kernel<<<2 * BATCH * (NPIX / 128), 256, 0, stream>>>(Opart, Mp, Lp, outp);
}

// Round 11
// 200.952 us; speedup vs baseline: 1.3845x; 1.0208x over previous
//
#include <hip/hip_runtime.h>

typedef float f4 __attribute__((ext_vector_type(4)));
typedef float f16v __attribute__((ext_vector_type(16)));
typedef _Float16 hf;
typedef __fp16 fp16x2 __attribute__((ext_vector_type(2)));
typedef hf h8 __attribute__((ext_vector_type(8)));
typedef unsigned short ushort_t;
typedef unsigned int uint_t;
typedef uint_t u4 __attribute__((ext_vector_type(4)));

#define BATCH 8
#define CH 128
#define NPIX 4096
#define LOG2E 1.4426950408889634f
#define RESCALE_THR 8.0f  // defer-max threshold (base-2 units); P bounded by 2^8

__device__ inline f16v mfma32h(h8 a, h8 b, f16v c) {
    return __builtin_amdgcn_mfma_f32_32x32x16_f16(a, b, c, 0, 0, 0);
}

__device__ inline uint_t pk2h(float a, float b) {  // pack 2 fp32 -> fp16x2 (RTZ), as u32
    fp16x2 pp = __builtin_amdgcn_cvt_pkrtz(a, b);
    union { fp16x2 v; uint_t u; } cv;
    cv.v = pp;
    return cv.u;
}

// after: a = {a_lo31, b_lo31}, b = {a_hi31, b_hi31}
__device__ inline void pl32swap(uint_t& a, uint_t& b) {
    asm("v_permlane32_swap_b32 %0, %1" : "+v"(a), "+v"(b));
}

typedef __attribute__((address_space(3))) uint_t lds_uint;
typedef __attribute__((address_space(1))) const uint_t global_uint;
__device__ inline void dma16(const void* g, void* l) {
    __builtin_amdgcn_global_load_lds((global_uint*)g, (lds_uint*)l, 16, 0, 0);
}

__device__ inline ushort_t h2u(hf x) {
    union { hf h; ushort_t u; } cv;
    cv.h = x;
    return cv.u;
}

// wait(own oldest DMAs) -> barrier -> pin schedule
#define WAITB(vm)                                                          \
    do {                                                                   \
        asm volatile("s_waitcnt vmcnt(" #vm ") lgkmcnt(0)" ::: "memory");  \
        __builtin_amdgcn_s_barrier();                                      \
        __builtin_amdgcn_sched_barrier(0);                                 \
    } while (0)

// ---------------- QKV projection via MFMA (fp16 hi/lo 2-pass) ----------------
// X converted to fp16 hi/lo ONCE into LDS; fragments via ds_read_b128.
// Q: [b][n][c] (log2e-scaled);  K: [b][n][c];  V: [b][c][n].  All fp16.
__global__ __launch_bounds__(256) void qkv_kernel(const float* __restrict__ x1,
                                                  const float* __restrict__ x2,
                                                  const float* __restrict__ Wq,
                                                  const float* __restrict__ Wk,
                                                  const float* __restrict__ Wv,
                                                  const float* __restrict__ bq,
                                                  const float* __restrict__ bk,
                                                  const float* __restrict__ bv,
                                                  hf* __restrict__ Qf, hf* __restrict__ Kf,
                                                  hf* __restrict__ Vf) {
    // XH/XL[n][c] fp16, 64 x 128, rows 256B = 16 slots of 16B; slot s stored at
    // s' = s ^ (n&15)  -> conflict-free b128 reads.
    __shared__ __align__(16) ushort_t XH[64 * 128];
    __shared__ __align__(16) ushort_t XL[64 * 128];

    int bid = blockIdx.x;
    int m = bid >> 9;          // 0:Q 1:K 2:V
    int rem = bid & 511;
    int b = rem & 7;
    int n0 = (rem >> 3) << 6;  // 64-px chunk

    const float* X = ((m == 0) ? x1 : x2) + (size_t)b * CH * NPIX;
    const float* bias = (m == 0) ? bq : (m == 1) ? bk : bv;

    int tid = threadIdx.x;
    // stage X fp32 -> cvt hi/lo fp16 -> LDS [n][c] swizzled (coalesced global reads)
#pragma unroll
    for (int r = 0; r < 8; ++r) {
        int c = 16 * r + (tid >> 4);
        int n4 = (tid & 15) << 2;
        f4 v = *(const f4*)&X[(size_t)c * NPIX + n0 + n4];
        int cs = c >> 3, cj = c & 7;
#pragma unroll
        for (int j = 0; j < 4; ++j) {
            int n = n4 + j;
            hf hi = (hf)v[j];
            hf lo = (hf)(v[j] - (float)hi);
            int ofs = n * 128 + ((cs ^ (n & 15)) << 3) + cj;
            XH[ofs] = h2u(hi);
            XL[ofs] = h2u(lo);
        }
    }

    int lane = tid & 63;
    int w = tid >> 6;
    int h = lane >> 5;
    int m32 = lane & 31;
    int o0 = w * 32;  // this wave's 32 output channels

    // W fragments: read fp32 row o0+m32 of W directly, convert in-reg (same element
    // set serves as A-frag (V path) and B-frag (Q/K path)).
    const float* Wsrc = (m == 0) ? Wq : (m == 1) ? Wk : Wv;
    float wscale = (m == 0) ? LOG2E : 1.0f;
    h8 wf[8];
    {
        const float* wrow = Wsrc + (size_t)(o0 + m32) * CH;
#pragma unroll
        for (int kc = 0; kc < 8; ++kc) {
            f4 a = *(const f4*)&wrow[kc * 16 + h * 8];
            f4 b2 = *(const f4*)&wrow[kc * 16 + h * 8 + 4];
            h8 t;
#pragma unroll
            for (int j = 0; j < 4; ++j) {
                t[j] = (hf)(a[j] * wscale);
                t[4 + j] = (hf)(b2[j] * wscale);
            }
            wf[kc] = t;
        }
    }

    __syncthreads();

    f16v acc[2];
#pragma unroll
    for (int g = 0; g < 2; ++g)
#pragma unroll
        for (int r = 0; r < 16; ++r) acc[g][r] = 0.f;

    int swzn = m32 & 15;  // n&15 for n = g*32+m32
#pragma unroll
    for (int g = 0; g < 2; ++g) {
        int nrow = (g * 32 + m32) * 128;
#pragma unroll
        for (int kc = 0; kc < 8; ++kc) {
            int sofs = nrow + (((kc * 2 + h) ^ swzn) << 3);
            h8 xh = *(const h8*)&XH[sofs];
            h8 xl = *(const h8*)&XL[sofs];
            if (m == 2) {  // V: D[o][n] = W . X
                acc[g] = mfma32h(wf[kc], xh, acc[g]);
                acc[g] = mfma32h(wf[kc], xl, acc[g]);
            } else {  // Q/K: D[n][o] = X^T . W^T
                acc[g] = mfma32h(xh, wf[kc], acc[g]);
                acc[g] = mfma32h(xl, wf[kc], acc[g]);
            }
        }
    }

    if (m < 2) {  // D[n][o]: col=o (lane), rows=n; store [b][n][c], lanes coalesced in o
        float bval = bias[o0 + m32] * ((m == 0) ? LOG2E : 1.0f);
        hf* Y = ((m == 0) ? Qf : Kf) + (size_t)b * NPIX * CH;
#pragma unroll
        for (int g = 0; g < 2; ++g)
#pragma unroll
            for (int r = 0; r < 16; ++r) {
                int n = n0 + g * 32 + (r & 3) + 8 * (r >> 2) + 4 * h;
                Y[(size_t)n * CH + o0 + m32] = (hf)(acc[g][r] + bval);
            }
    } else {  // D[o][n]: col=n (lane), rows=o; store [b][c][n], lanes coalesced in n
        hf* Yv = Vf + (size_t)b * CH * NPIX;
#pragma unroll
        for (int g = 0; g < 2; ++g)
#pragma unroll
            for (int r = 0; r < 16; ++r) {
                int o = o0 + (r & 3) + 8 * (r >> 2) + 4 * h;
                Yv[(size_t)o * NPIX + n0 + g * 32 + m32] = (hf)(acc[g][r] + bias[o]);
            }
    }
}

// ---------------- fp16 MFMA flash attention, 2-way split-K, 4x(32q x 32k) waves ----------------
// grid: 8b * 2ksides * 32qtiles = 512 blocks = exactly 2/CU, all resident (no batching).
// Each wave owns 32 queries over the full 32-key tile -> no cross-wave merge epilogue.
// 4-deep tile pipeline, compile-time buffer indices (4x-unrolled loop):
//   WAITB(8)  [own tile-t DMAs retired; tiles t+1,t+2 in flight]  -> barrier
//   issue tile t+3 into buf (t+3)&3  [== (t-1)&3, freed by the barrier]
//   compute tile t from buf t&3
// vmcnt never drains to 0 until the last tile. 64 iters (2048 keys).
// NOTE (R4/R10 lessons): register-edge kernel — any added live state (dual QK
// accumulators, merged tt buffer) regresses via pressure/spill. Keep comp() lean.
__global__ __launch_bounds__(256, 2) void attn_kernel(const hf* __restrict__ Qf,
                                                      const hf* __restrict__ Kf,
                                                      const hf* __restrict__ Vf,
                                                      hf* __restrict__ Opart,
                                                      float* __restrict__ Mpart,
                                                      float* __restrict__ Lpart) {
    __shared__ __align__(16) ushort_t smem[32768];  // 64 KB

    int tid = threadIdx.x;
    int lane = tid & 63;
    int w = tid >> 6;        // wave = query group
    int h = lane >> 5;
    int m32 = lane & 31;

    int idx = blockIdx.x;
    int b = idx & 7;             // batch <-> XCD
    int ks = (idx >> 3) & 1;     // key half
    int qt = idx >> 4;           // query tile (128 q)
    int q0 = (qt << 7) + w * 32; // this wave's first query
    int k0g = ks << 11;          // 2048-key base

    const hf* Qb = Qf + (size_t)b * NPIX * CH;
    const hf* Kb = Kf + (size_t)b * NPIX * CH;
    const hf* Vb = Vf + (size_t)b * CH * NPIX;

    // Q B-frags (col = q0+m32), registers for whole loop
    h8 qf[8];
#pragma unroll
    for (int kc = 0; kc < 8; ++kc)
        qf[kc] = *(const h8*)&Qb[(size_t)(q0 + m32) * CH + kc * 16 + h * 8];

    // DMA source pointers (XOR swizzle folded into global address)
    // K tile: [32 rows][128 ch] = 8 KB, 256B rows = 16 slots; slot ^ (row&15).
    // V tile: [128 ch][32 k]   = 8 KB,  64B rows; slot ^ (c&3) ^ ((c>>2)&1).
    const hf* pK[2];
    const hf* pV[2];
#pragma unroll
    for (int a = 0; a < 2; ++a) {
        int chunk_hi = w * 2 + a;  // 0..7
        int rowk = chunk_hi * 4 + (lane >> 4);           // 0..31
        int lck = (lane & 15) ^ (rowk & 15);
        pK[a] = Kb + (size_t)(k0g + rowk) * CH + lck * 8;
        int rowv = chunk_hi * 16 + (lane >> 2);          // 0..127 (= channel)
        int lcv = (lane & 3) ^ (rowv & 3) ^ ((rowv >> 2) & 1);
        pV[a] = Vb + (size_t)rowv * NPIX + k0g + lcv * 8;
    }

    f16v accO[4];
#pragma unroll
    for (int ct = 0; ct < 4; ++ct)
#pragma unroll
        for (int r = 0; r < 16; ++r) accO[ct][r] = 0.f;
    float mprev = -1e30f;  // per-query running max (base-2 units)
    float lsum = 0.f;      // per-HALF partial sum (merged once in epilogue)

    int pvs[2];
#pragma unroll
    for (int g2 = 0; g2 < 2; ++g2)
        pvs[g2] = (g2 * 2 + h) ^ (m32 & 3) ^ ((m32 >> 2) & 1);

    // stage one 32-key tile into buffer bufw (compile-time), advance pointers
    auto stage = [&](int bufw) {
#pragma unroll
        for (int a = 0; a < 2; ++a) {
            dma16(pK[a], &smem[bufw * 4096 + (w * 2 + a) * 512]);
            dma16(pV[a], &smem[16384 + bufw * 4096 + (w * 2 + a) * 512]);
            pK[a] += 32 * CH;
            pV[a] += 32;
        }
    };

    // compute one 32-key tile from buffer bufr (compile-time)
    auto comp = [&](int bufr) {
        const ushort_t* kb = smem + bufr * 4096;
        const ushort_t* vb = smem + 16384 + bufr * 4096;

        // --- S^T[key][query] = K . Q^T (32 keys x this wave's 32 queries) ---
        f16v acc;
#pragma unroll
        for (int r = 0; r < 16; ++r) acc[r] = 0.f;
        __builtin_amdgcn_s_setprio(1);
#pragma unroll
        for (int kc = 0; kc < 8; ++kc) {
            int pA = (kc * 2 + h) ^ (m32 & 15);
            h8 ahi = *(const h8*)&kb[m32 * 128 + pA * 8];
            acc = mfma32h(ahi, qf[kc], acc);
        }
        __builtin_amdgcn_s_setprio(0);

        // --- wave-private online softmax (base-2 units, deferred max) ---
        // per-half max; __any spans all 64 lanes so the p<=2^THR bound still holds
        float ta = fmaxf(fmaxf(acc[0], acc[1]), acc[2]);
        float tb = fmaxf(fmaxf(acc[3], acc[4]), acc[5]);
        ta = fmaxf(fmaxf(ta, acc[6]), acc[7]);
        tb = fmaxf(fmaxf(tb, acc[8]), acc[9]);
        ta = fmaxf(fmaxf(ta, acc[10]), acc[11]);
        tb = fmaxf(fmaxf(tb, acc[12]), acc[13]);
        ta = fmaxf(fmaxf(ta, acc[14]), acc[15]);
        float tmax = fmaxf(ta, tb);  // this half's tile max for query m32
        if (__any(tmax > mprev + RESCALE_THR)) {
            float tx = fmaxf(tmax, __shfl_xor(tmax, 32));  // exact cross-half max
            float mnew = fmaxf(mprev, tx);
            float alpha = exp2f(mprev - mnew);
            lsum *= alpha;
#pragma unroll
            for (int ct = 0; ct < 4; ++ct)
#pragma unroll
                for (int r = 0; r < 16; ++r) accO[ct][r] *= alpha;
            mprev = mnew;
        }

        // exp2 + pack + per-half row-sum (cross-half merge deferred to epilogue)
        uint_t pk[8];
        float ps0 = 0.f, ps1 = 0.f;
#pragma unroll
        for (int t2 = 0; t2 < 8; ++t2) {
            float e0 = exp2f(acc[2 * t2] - mprev);
            float e1 = exp2f(acc[2 * t2 + 1] - mprev);
            ps0 += e0;
            ps1 += e1;
            pk[t2] = pk2h(e0, e1);
        }
        lsum += ps0 + ps1;

        // both-half P fragments via permlane32_swap
        pl32swap(pk[0], pk[2]);
        pl32swap(pk[1], pk[3]);
        pl32swap(pk[4], pk[6]);
        pl32swap(pk[5], pk[7]);
        h8 pbp[2];
#pragma unroll
        for (int g2 = 0; g2 < 2; ++g2) {
            u4 fv;
            fv[0] = pk[g2 * 4 + 0];
            fv[1] = pk[g2 * 4 + 1];
            fv[2] = pk[g2 * 4 + 2];
            fv[3] = pk[g2 * 4 + 3];
            __builtin_memcpy(&pbp[g2], &fv, 16);
        }

        // --- O^T[c][q] += V . P ---
        __builtin_amdgcn_s_setprio(1);
#pragma unroll
        for (int g2 = 0; g2 < 2; ++g2) {
            int pv = pvs[g2];
#pragma unroll
            for (int ct = 0; ct < 4; ++ct) {
                h8 av = *(const h8*)&vb[(ct * 32 + m32) * 32 + pv * 8];
                accO[ct] = mfma32h(av, pbp[g2], accO[ct]);
            }
        }
        __builtin_amdgcn_s_setprio(0);
    };

    // prologue: tiles 0,1,2 -> bufs 0,1,2 (12 DMAs in flight)
    stage(0);
    stage(1);
    stage(2);

    // main loop: t = 0..59 (4x unrolled, compile-time buffer indices)
    for (int tb = 0; tb < 15; ++tb) {
        WAITB(8); stage(3); comp(0);
        WAITB(8); stage(0); comp(1);
        WAITB(8); stage(1); comp(2);
        WAITB(8); stage(2); comp(3);
    }
    // t = 60..63
    WAITB(8); stage(3); comp(0);  // issues tile 63 (last)
    WAITB(8); comp(1);
    WAITB(4); comp(2);
    WAITB(0); comp(3);

    // --- epilogue: merge half-sums once; each wave owns its 32 q fully ---
    lsum += __shfl_xor(lsum, 32);

    size_t base = (((size_t)ks * 8 + b) * 32 + qt) * 16384;
    size_t mlb = (((size_t)ks * 8 + b) * 32 + qt) * 128;
    int q = w * 32 + m32;
#pragma unroll
    for (int ct = 0; ct < 4; ++ct)
#pragma unroll
        for (int r = 0; r < 16; ++r) {
            int ch = ct * 32 + (r & 3) + 8 * (r >> 2) + 4 * h;
            Opart[base + ch * 128 + q] = (hf)accO[ct][r];
        }
    if (h == 0) {
        Mpart[mlb + q] = mprev;
        Lpart[mlb + q] = lsum;
    }
}

// ---------------- combine the two key-half partials (vectorized) ----------------
__global__ __launch_bounds__(256) void combine_kernel(const hf* __restrict__ Opart,
                                                      const float* __restrict__ Mp,
                                                      const float* __restrict__ Lp,
                                                      float* __restrict__ out) {
    int idx = blockIdx.x;        // 512 = 2chh x 8b x 32qt
    int chh = idx & 1;
    int b = (idx >> 1) & 7;
    int qt = idx >> 4;
    int tid = threadIdx.x;
    int q8 = (tid & 15) << 3;    // 8 consecutive queries
    int chl = tid >> 4;          // 0..15

    size_t tile = (size_t)b * 32 + qt;

    float Marr[2][8], Larr[2][8];
#pragma unroll
    for (int p = 0; p < 2; ++p) {
        const float* mp_ = Mp + ((size_t)p * 256 + tile) * 128 + q8;
        const float* lp_ = Lp + ((size_t)p * 256 + tile) * 128 + q8;
        f4 ma = *(const f4*)mp_;
        f4 mb = *(const f4*)(mp_ + 4);
        f4 la = *(const f4*)lp_;
        f4 lb = *(const f4*)(lp_ + 4);
#pragma unroll
        for (int j = 0; j < 4; ++j) {
            Marr[p][j] = ma[j];
            Marr[p][4 + j] = mb[j];
            Larr[p][j] = la[j];
            Larr[p][4 + j] = lb[j];
        }
    }

    float wgt[2][8];
#pragma unroll
    for (int j = 0; j < 8; ++j) {
        float M = fmaxf(Marr[0][j], Marr[1][j]);
        float w0 = exp2f(Marr[0][j] - M);
        float w1 = exp2f(Marr[1][j] - M);
        float rd = 1.0f / (w0 * Larr[0][j] + w1 * Larr[1][j]);
        wgt[0][j] = w0 * rd;
        wgt[1][j] = w1 * rd;
    }

    const hf* ob[2];
#pragma unroll
    for (int p = 0; p < 2; ++p) ob[p] = Opart + ((size_t)p * 256 + tile) * 16384 + q8;
    float* O = out + (size_t)b * CH * NPIX + (size_t)qt * 128 + q8;

#pragma unroll
    for (int it = 0; it < 4; ++it) {
        int ch = chh * 64 + it * 16 + chl;
        union { u4 u; h8 v; } o4[2];
#pragma unroll
        for (int p = 0; p < 2; ++p) o4[p].u = *(const u4*)&ob[p][(size_t)ch * 128];
        f4 r0, r1;
#pragma unroll
        for (int j = 0; j < 8; ++j) {
            float s = wgt[0][j] * (float)o4[0].v[j] + wgt[1][j] * (float)o4[1].v[j];
            if (j < 4) r0[j] = s;
            else r1[j - 4] = s;
        }
        float* dst = O + (size_t)ch * NPIX;
        *(f4*)dst = r0;
        *(f4*)(dst + 4) = r1;
    }
}

extern "C" void kernel_launch(void* const* d_in, const int* in_sizes, int n_in,
                              void* d_out, int out_size, void* d_ws, size_t ws_size,
                              hipStream_t stream) {
    const float* x1 = (const float*)d_in[0];
    const float* x2 = (const float*)d_in[1];
    const float* Wq = (const float*)d_in[2];
    const float* bq = (const float*)d_in[3];
    const float* Wk = (const float*)d_in[4];
    const float* bk = (const float*)d_in[5];
    const float* Wv = (const float*)d_in[6];
    const float* bv = (const float*)d_in[7];
    float* outp = (float*)d_out;

    const size_t N = (size_t)BATCH * NPIX * CH;  // 4.19M
    hf* Qf = (hf*)d_ws;
    hf* Kf = Qf + N;
    hf* Vf = Qf + 2 * N;
    hf* Opart = Qf + 3 * N;                              // 2*8*32*16384 hf = 16.8 MB
    float* Mp = (float*)(Opart + (size_t)2 * 8 * 32 * 16384);
    float* Lp = Mp + (size_t)2 * 8 * 32 * 128;

    qkv_kernel<<<3 * BATCH * (NPIX / 64), 256, 0, stream>>>(x1, x2, Wq, Wk, Wv,
                                                            bq, bk, bv, Qf, Kf, Vf);
    attn_kernel<<<BATCH * 2 * (NPIX / 128), 256, 0, stream>>>(Qf, Kf, Vf, Opart, Mp, Lp);
    combine_kernel<<<2 * BATCH * (NPIX / 128), 256, 0, stream>>>(Opart, Mp, Lp, outp);
}